// Round 6
// baseline (324.276 us; speedup 1.0000x reference)
//
#include <hip/hip_runtime.h>
#include <math.h>

#define D_   512
#define H_   8
#define DK_  64
#define FF_  2048
#define S_   2048
#define B_   4
#define M_   (B_*S_)     // 8192
#define EPS_ 1e-5f

typedef __attribute__((ext_vector_type(8))) short bf16x8;
typedef __attribute__((ext_vector_type(4))) float f32x4;

__device__ inline unsigned short f2b(float f) {
    unsigned u = __builtin_bit_cast(unsigned, f);
    unsigned r = (u + 0x7FFFu + ((u >> 16) & 1u)) >> 16;
    return (unsigned short)r;
}
// truncation (1 VALU op) — used only for P in [0,1]
__device__ inline unsigned short f2b_trunc(float f) {
    return (unsigned short)(__builtin_bit_cast(unsigned, f) >> 16);
}

// async 16B global->LDS (m97). LDS dest must be wave-uniform base + lane*16.
__device__ __forceinline__ void async_cp16(const void* g, void* l) {
    __builtin_amdgcn_global_load_lds(
        (const __attribute__((address_space(1))) unsigned int*)g,
        (__attribute__((address_space(3))) unsigned int*)l, 16, 0, 0);
}

// ---------------------------------------------------------------------------
__global__ __launch_bounds__(256)
void convert_bf16(const float* __restrict__ src, unsigned short* __restrict__ dst)
{
    const int i = (blockIdx.x * 256 + threadIdx.x) * 8;
    const float4 a = *(const float4*)(src + i);
    const float4 b = *(const float4*)(src + i + 4);
    bf16x8 v;
    v[0] = (short)f2b(a.x); v[1] = (short)f2b(a.y);
    v[2] = (short)f2b(a.z); v[3] = (short)f2b(a.w);
    v[4] = (short)f2b(b.x); v[5] = (short)f2b(b.y);
    v[6] = (short)f2b(b.z); v[7] = (short)f2b(b.w);
    *(bf16x8*)(dst + i) = v;
}

// ---------------------------------------------------------------------------
__global__ __launch_bounds__(256)
void wtrans(const float* __restrict__ w, unsigned short* __restrict__ wt, int K, int N)
{
    __shared__ float L[32][33];
    const int k0 = blockIdx.y * 32, n0 = blockIdx.x * 32;
    const int x = threadIdx.x & 31, y = threadIdx.x >> 5;
#pragma unroll
    for (int i = 0; i < 4; i++)
        L[y + i * 8][x] = w[(size_t)(k0 + y + i * 8) * N + n0 + x];
    __syncthreads();
#pragma unroll
    for (int i = 0; i < 4; i++)
        wt[(size_t)(n0 + y + i * 8) * K + k0 + x] = f2b(L[x][y + i * 8]);
}

// ---------------------------------------------------------------------------
// Fused transpose for the four 512x512 weights + bqkv pack.
// ---------------------------------------------------------------------------
__global__ __launch_bounds__(256)
void wtrans4(const float* __restrict__ wq, const float* __restrict__ wk,
             const float* __restrict__ wv, const float* __restrict__ wo,
             const float* __restrict__ bq, const float* __restrict__ bk,
             const float* __restrict__ bv,
             unsigned short* __restrict__ wqkvt, unsigned short* __restrict__ wot,
             float* __restrict__ bqkv)
{
    __shared__ float L[32][33];
    const int z = blockIdx.z;
    const float* w = (z == 0) ? wq : (z == 1) ? wk : (z == 2) ? wv : wo;
    unsigned short* wt = (z < 3) ? (wqkvt + (size_t)z * 512 * 512) : wot;
    const int k0 = blockIdx.y * 32, n0 = blockIdx.x * 32;
    const int x = threadIdx.x & 31, y = threadIdx.x >> 5;
#pragma unroll
    for (int i = 0; i < 4; i++)
        L[y + i * 8][x] = w[(size_t)(k0 + y + i * 8) * 512 + n0 + x];
    __syncthreads();
#pragma unroll
    for (int i = 0; i < 4; i++)
        wt[(size_t)(n0 + y + i * 8) * 512 + k0 + x] = f2b(L[x][y + i * 8]);
    if (z < 3 && blockIdx.x == 0 && blockIdx.y == 0) {
        const float* bsrc = (z == 0) ? bq : (z == 1) ? bk : bv;
        const int t = threadIdx.x;
        bqkv[z * 512 + t]       = bsrc[t];
        bqkv[z * 512 + 256 + t] = bsrc[256 + t];
    }
}

// ---------------------------------------------------------------------------
// bf16 MFMA GEMM (m97 structure). Tile BM x BN, BK=32, 4 waves.
// A [*][lda] bf16, Bt [*][ldb] bf16. Loop K. Optional fp32 residual (C-layout).
// ---------------------------------------------------------------------------
template<int WR, int WC, int MT, int NT, int OUTB, int RELU, int RESADD, int HASBIAS>
__global__ __launch_bounds__(256)
void gemm_bf16(const unsigned short* __restrict__ A, const unsigned short* __restrict__ Bt,
               const float* __restrict__ bias, const float* __restrict__ RES,
               void* __restrict__ Cv, int K, int lda, int ldb, int ldc)
{
    constexpr int BM = WR * MT * 16;
    constexpr int BN = WC * NT * 16;
    __shared__ unsigned short As[BM * 32];
    __shared__ unsigned short Bs[BN * 32];

    const int tid  = threadIdx.x;
    const int lane = tid & 63;
    const int w    = tid >> 6;
    const int wr   = w / WC, wc = w % WC;
    const int quad = lane >> 4;
    const int l15  = lane & 15;
    const int n0   = blockIdx.x * BN;
    const int m0   = blockIdx.y * BM;

    f32x4 acc[MT][NT];
#pragma unroll
    for (int i = 0; i < MT; i++)
#pragma unroll
        for (int j = 0; j < NT; j++) acc[i][j] = (f32x4){0.f, 0.f, 0.f, 0.f};

    constexpr int CA = BM / 64;
    constexpr int CB = BN / 64;

    for (int k0 = 0; k0 < K; k0 += 32) {
        __syncthreads();
#pragma unroll
        for (int i = 0; i < CA; i++) {
            const int c = tid + i * 256;
            async_cp16(&A[(size_t)(m0 + (c >> 2)) * lda + k0 + (c & 3) * 8], &As[c * 8]);
        }
#pragma unroll
        for (int i = 0; i < CB; i++) {
            const int c = tid + i * 256;
            async_cp16(&Bt[(size_t)(n0 + (c >> 2)) * ldb + k0 + (c & 3) * 8], &Bs[c * 8]);
        }
        __builtin_amdgcn_s_waitcnt(0x0f70);       // vmcnt(0)
        __syncthreads();

        bf16x8 af[MT], bfr[NT];
#pragma unroll
        for (int t = 0; t < MT; t++)
            af[t]  = *(const bf16x8*)&As[(wr * MT * 16 + t * 16 + l15) * 32 + quad * 8];
#pragma unroll
        for (int t = 0; t < NT; t++)
            bfr[t] = *(const bf16x8*)&Bs[(wc * NT * 16 + t * 16 + l15) * 32 + quad * 8];
#pragma unroll
        for (int mt = 0; mt < MT; mt++)
#pragma unroll
            for (int nt = 0; nt < NT; nt++)
                acc[mt][nt] = __builtin_amdgcn_mfma_f32_16x16x32_bf16(
                    af[mt], bfr[nt], acc[mt][nt], 0, 0, 0);
    }

    // epilogue: C/D layout col=lane&15, row=quad*4+reg
#pragma unroll
    for (int mt = 0; mt < MT; mt++) {
        const int rowb = m0 + wr * MT * 16 + mt * 16 + quad * 4;
#pragma unroll
        for (int nt = 0; nt < NT; nt++) {
            const int col = n0 + wc * NT * 16 + nt * 16 + l15;
            const float bv = HASBIAS ? bias[col] : 0.f;
#pragma unroll
            for (int r = 0; r < 4; r++) {
                const size_t idx = (size_t)(rowb + r) * ldc + col;
                float v = acc[mt][nt][r] + bv;
                if (RESADD) v += RES[idx];
                if (RELU)   v = fmaxf(v, 0.f);
                if (OUTB) ((unsigned short*)Cv)[idx] = f2b(v);
                else      ((float*)Cv)[idx] = v;
            }
        }
    }
}

// ---------------------------------------------------------------------------
// V transpose: qkv v-part [s][dk] per (b,h) -> vt [(b*8+h)*64+dk][s] bf16.
// ---------------------------------------------------------------------------
__global__ __launch_bounds__(256)
void vtrans(const unsigned short* __restrict__ qkv, unsigned short* __restrict__ vt)
{
    __shared__ unsigned short L[64][72];
    const int s0 = blockIdx.x * 64;
    const int bh = blockIdx.y;
    const int b  = bh >> 3, hh = bh & 7;
    const int tid = threadIdx.x;
    const unsigned short* src = qkv + (size_t)(b * S_) * 1536 + 1024 + hh * 64;
#pragma unroll
    for (int i = 0; i < 2; i++) {
        const int c = tid + i * 256;
        const int r = c >> 3, sub = (c & 7) * 8;
        *(bf16x8*)&L[r][sub] = *(const bf16x8*)(src + (size_t)(s0 + r) * 1536 + sub);
    }
    __syncthreads();
    const int dk = tid >> 2;
    const int sc = (tid & 3) * 16;
    bf16x8 t0, t1;
#pragma unroll
    for (int j = 0; j < 8; j++) t0[j] = (short)L[sc + j][dk];
#pragma unroll
    for (int j = 0; j < 8; j++) t1[j] = (short)L[sc + 8 + j][dk];
    unsigned short* dst = vt + (size_t)(bh * 64 + dk) * S_ + s0 + sc;
    *(bf16x8*)(dst)     = t0;
    *(bf16x8*)(dst + 8) = t1;
}

// ---------------------------------------------------------------------------
// Causal flash attention, bf16 MFMA. BQ=64 (4 waves x 16 q-rows), KB=128.
// BALANCED PAIRING: block i handles qb=31-i then qb=i -> every block does
// exactly 17 k-iterations (kills the causal load-imbalance tail).
// Row-sum via MFMA ones-column (Oacc[4]): no per-iter sum shuffles.
// ---------------------------------------------------------------------------
__global__ __launch_bounds__(256)
void attn_mfma(const unsigned short* __restrict__ qkv,
               const unsigned short* __restrict__ vt,
               unsigned short* __restrict__ ctx)
{
    constexpr int LDP = 136;
    __shared__ unsigned short Ks[128 * 64];   // [kr][d], chunk^=(kr&7)
    __shared__ unsigned short Vs[80 * 128];   // [dk][kr], chunk^=(dk&15); row64=ones
    __shared__ unsigned short Ps[4][16 * LDP];

    const int tid  = threadIdx.x;
    const int lane = tid & 63;
    const int w    = tid >> 6;                // 0..3
    const int quad = lane >> 4;
    const int l15  = lane & 15;
    const int pi   = blockIdx.x >> 5;         // 0..15 pair index
    const int bh   = blockIdx.x & 31;
    const int b    = bh >> 3, hh = bh & 7;

    const unsigned short* qbase = qkv + (size_t)(b * S_) * 1536 + hh * 64;
    const unsigned short* kbase = qbase + 512;
    const unsigned short* vtb   = vt + (size_t)bh * 64 * S_;
    unsigned short* pw = &Ps[w][0];

    // init rows 64..79 of Vs: row 64 = ones (for l), rest zero. One-time.
    {
        const int c = tid * 8;                // 0..2047 covers 16 rows x 128
        const int row = c >> 7;
        bf16x8 fill;
        const short v = (row == 0) ? (short)0x3F80 : (short)0;
#pragma unroll
        for (int j = 0; j < 8; j++) fill[j] = v;
        *(bf16x8*)&Vs[64 * 128 + c] = fill;
    }

    const float SCL = 0.125f * 1.44269504089f; // 1/sqrt(64) * log2(e)

    for (int phase = 0; phase < 2; phase++) {
        const int qb  = phase ? pi : (31 - pi);
        const int nkb = (qb >> 1) + 1;
        const int qg0 = qb * 64 + w * 16 + quad * 4;
        const int klim = qb * 64 + w * 16 + 15;
        const int kcmax_diag = (klim - (nkb - 1) * 128) / 32 + 1;

        bf16x8 qf[2];
        {
            const unsigned short* qr = qbase + (size_t)(qb * 64 + w * 16 + l15) * 1536;
            qf[0] = *(const bf16x8*)(qr + quad * 8);
            qf[1] = *(const bf16x8*)(qr + 32 + quad * 8);
        }

        f32x4 Oacc[5];                         // [4] = row-sum (ones column)
#pragma unroll
        for (int i = 0; i < 5; i++) Oacc[i] = (f32x4){0.f, 0.f, 0.f, 0.f};
        float mrow[4];
#pragma unroll
        for (int r = 0; r < 4; r++) mrow[r] = -1.0e30f;

        for (int kb = 0; kb < nkb; kb++) {
            __syncthreads();
#pragma unroll
            for (int i = 0; i < 4; i++) {      // K tile: 1024 chunks / 256 thr
                const int c = tid + i * 256;
                const int row = c >> 3;
                const int l = (c & 7) ^ (row & 7);
                async_cp16(kbase + (size_t)(kb * 128 + row) * 1536 + l * 8, &Ks[c * 8]);
            }
#pragma unroll
            for (int i = 0; i < 4; i++) {      // V^T tile rows 0..63
                const int c = tid + i * 256;
                const int row = c >> 4;
                const int l = (c & 15) ^ (row & 15);
                async_cp16(vtb + (size_t)row * S_ + kb * 128 + l * 8, &Vs[c * 8]);
            }
            __builtin_amdgcn_s_waitcnt(0x0f70);  // vmcnt(0)
            __syncthreads();

            const bool diag = (kb == nkb - 1);

            // ---- S = Q @ K^T over 8 key tiles (skip fully-masked)
            f32x4 sacc[8];
#pragma unroll
            for (int nt = 0; nt < 8; nt++) sacc[nt] = (f32x4){0.f, 0.f, 0.f, 0.f};
#pragma unroll
            for (int nt = 0; nt < 8; nt++) {
                if (diag && (kb * 128 + nt * 16 > klim)) continue;
#pragma unroll
                for (int kc = 0; kc < 2; kc++) {
                    const int phys = (kc * 4 + quad) ^ (l15 & 7);
                    const bf16x8 kf = *(const bf16x8*)&Ks[(nt * 16 + l15) * 64 + phys * 8];
                    sacc[nt] = __builtin_amdgcn_mfma_f32_16x16x32_bf16(qf[kc], kf, sacc[nt], 0, 0, 0);
                }
            }

            // ---- online softmax (raw-domain max; sums via MFMA ones-col)
            float alpha[4];
#pragma unroll
            for (int r = 0; r < 4; r++) {
                float sv[8];
#pragma unroll
                for (int nt = 0; nt < 8; nt++) {
                    float s = sacc[nt][r];
                    if (diag) {
                        const int kg = kb * 128 + nt * 16 + l15;
                        if (kg > qg0 + r) s = -1.0e9f;
                    }
                    sv[nt] = s;
                }
                float m0 = fmaxf(fmaxf(sv[0], sv[1]), fmaxf(sv[2], sv[3]));
                float m1 = fmaxf(fmaxf(sv[4], sv[5]), fmaxf(sv[6], sv[7]));
                float rmax = fmaxf(m0, m1);
#pragma unroll
                for (int m = 1; m < 16; m <<= 1) rmax = fmaxf(rmax, __shfl_xor(rmax, m));
                const float mnew = fmaxf(mrow[r], rmax);
                alpha[r] = exp2f((mrow[r] - mnew) * SCL);
                const float negms = -mnew * SCL;
#pragma unroll
                for (int nt = 0; nt < 8; nt++) {
                    sv[nt] = exp2f(fmaf(sv[nt], SCL, negms));
                    pw[(quad * 4 + r) * LDP + nt * 16 + l15] = f2b_trunc(sv[nt]);
                }
                mrow[r] = mnew;
            }
#pragma unroll
            for (int nt = 0; nt < 5; nt++)
#pragma unroll
                for (int r = 0; r < 4; r++) Oacc[nt][r] *= alpha[r];

            // ---- O += P @ V; Oacc[4] += P @ ones (row-sum)
            const int kcmax = diag ? kcmax_diag : 4;
#pragma unroll
            for (int kc = 0; kc < 4; kc++) {
                if (kc < kcmax) {
                    const bf16x8 af = *(const bf16x8*)&pw[l15 * LDP + kc * 32 + quad * 8];
#pragma unroll
                    for (int nt = 0; nt < 5; nt++) {
                        const int phys = (kc * 4 + quad) ^ l15;
                        const bf16x8 vf = *(const bf16x8*)&Vs[(nt * 16 + l15) * 128 + phys * 8];
                        Oacc[nt] = __builtin_amdgcn_mfma_f32_16x16x32_bf16(af, vf, Oacc[nt], 0, 0, 0);
                    }
                }
            }
        }

        // ---- normalize (row-sum lives in lane quad*16, col 0) + write ctx
        const int orow = qb * 64 + w * 16 + quad * 4;
        unsigned short* cb = ctx + (size_t)(b * S_) * 512 + hh * 64;
#pragma unroll
        for (int r = 0; r < 4; r++) {
            const float lsum = __shfl(Oacc[4][r], (lane & 48));
            const float inv = 1.f / lsum;
#pragma unroll
            for (int nt = 0; nt < 4; nt++)
                cb[(size_t)(orow + r) * 512 + nt * 16 + l15] = f2b(Oacc[nt][r] * inv);
        }
    }
}

// ---------------------------------------------------------------------------
// out = LayerNorm(sum of NSUM inputs) * g + be.  1 wave/row.
// ---------------------------------------------------------------------------
template<int WB, int NSUM>
__global__ __launch_bounds__(256)
void ln_kernel(const float* __restrict__ s0p, const float* __restrict__ s1p,
               const float* __restrict__ g, const float* __restrict__ be,
               float* __restrict__ out, unsigned short* __restrict__ outb)
{
    const int wave = threadIdx.x >> 6;
    const int lane = threadIdx.x & 63;
    const int row  = blockIdx.x * 4 + wave;
    const float* p0 = s0p + (size_t)row * D_;
    const int c0 = lane * 4;

    float v[8];
    {
        const float4 a0 = *(const float4*)(p0 + c0);
        const float4 a1 = *(const float4*)(p0 + c0 + 256);
        v[0] = a0.x; v[1] = a0.y; v[2] = a0.z; v[3] = a0.w;
        v[4] = a1.x; v[5] = a1.y; v[6] = a1.z; v[7] = a1.w;
        if (NSUM == 2) {
            const float* p1 = s1p + (size_t)row * D_;
            const float4 b0 = *(const float4*)(p1 + c0);
            const float4 b1 = *(const float4*)(p1 + c0 + 256);
            v[0] += b0.x; v[1] += b0.y; v[2] += b0.z; v[3] += b0.w;
            v[4] += b1.x; v[5] += b1.y; v[6] += b1.z; v[7] += b1.w;
        }
    }

    float sum = 0.f;
#pragma unroll
    for (int i = 0; i < 8; i++) sum += v[i];
#pragma unroll
    for (int m = 1; m < 64; m <<= 1) sum += __shfl_xor(sum, m);
    const float mu = sum * (1.f / D_);

    float sq = 0.f;
#pragma unroll
    for (int i = 0; i < 8; i++) { const float d = v[i] - mu; sq += d * d; }
#pragma unroll
    for (int m = 1; m < 64; m <<= 1) sq += __shfl_xor(sq, m);
    const float rstd = rsqrtf(sq * (1.f / D_) + EPS_);

    const float4 g0 = *(const float4*)(g + c0);
    const float4 b0 = *(const float4*)(be + c0);
    const float4 g1 = *(const float4*)(g + c0 + 256);
    const float4 b1 = *(const float4*)(be + c0 + 256);

    float o[8];
    o[0] = (v[0] - mu) * rstd * g0.x + b0.x;
    o[1] = (v[1] - mu) * rstd * g0.y + b0.y;
    o[2] = (v[2] - mu) * rstd * g0.z + b0.z;
    o[3] = (v[3] - mu) * rstd * g0.w + b0.w;
    o[4] = (v[4] - mu) * rstd * g1.x + b1.x;
    o[5] = (v[5] - mu) * rstd * g1.y + b1.y;
    o[6] = (v[6] - mu) * rstd * g1.z + b1.z;
    o[7] = (v[7] - mu) * rstd * g1.w + b1.w;

    *(float4*)(out + (size_t)row * D_ + c0)       = *(float4*)&o[0];
    *(float4*)(out + (size_t)row * D_ + c0 + 256) = *(float4*)&o[4];
    if (WB) {
        short4 vb0 = (short4){(short)f2b(o[0]), (short)f2b(o[1]), (short)f2b(o[2]), (short)f2b(o[3])};
        short4 vb1 = (short4){(short)f2b(o[4]), (short)f2b(o[5]), (short)f2b(o[6]), (short)f2b(o[7])};
        *(short4*)(outb + (size_t)row * D_ + c0)       = vb0;
        *(short4*)(outb + (size_t)row * D_ + c0 + 256) = vb1;
    }
}

// ---------------------------------------------------------------------------
extern "C" void kernel_launch(void* const* d_in, const int* in_sizes, int n_in,
                              void* d_out, int out_size, void* d_ws, size_t ws_size,
                              hipStream_t stream)
{
    const float* x  = (const float*)d_in[0];
    const float* wq = (const float*)d_in[2];
    const float* bq = (const float*)d_in[3];
    const float* wk = (const float*)d_in[4];
    const float* bk = (const float*)d_in[5];
    const float* wv = (const float*)d_in[6];
    const float* bv = (const float*)d_in[7];
    const float* wo = (const float*)d_in[8];
    const float* bo = (const float*)d_in[9];
    const float* w1 = (const float*)d_in[10];
    const float* b1 = (const float*)d_in[11];
    const float* w2 = (const float*)d_in[12];
    const float* b2 = (const float*)d_in[13];
    const float* g1 = (const float*)d_in[14];
    const float* be1= (const float*)d_in[15];
    const float* g2 = (const float*)d_in[16];
    const float* be2= (const float*)d_in[17];
    float* out = (float*)d_out;

    const size_t MB = 1048576;
    char* w8 = (char*)d_ws;
    unsigned short* wqkvt = (unsigned short*)(w8 + 0);            // 1536x512 bf16
    unsigned short* wot   = (unsigned short*)(w8 + 1572864);      // 512x512
    unsigned short* w1t   = (unsigned short*)(w8 + 2097152);      // 2048x512
    unsigned short* w2t   = (unsigned short*)(w8 + 4194304);      // 512x2048
    float*          bqkv  = (float*)(w8 + 6291456);               // 1536 f32
    unsigned short* qkv   = (unsigned short*)(w8 + 8 * MB);       // 24 MB (later ffn1b 32MB)
    unsigned short* ffn1b = qkv;
    unsigned short* xb    = (unsigned short*)(w8 + 40 * MB);      // 8 MB (later ctx, then pre2)
    unsigned short* ctx   = xb;
    float*          pre2  = (float*)(w8 + 40 * MB);               // 16 MB (40..56, ctx+hb dead)
    unsigned short* vt    = (unsigned short*)(w8 + 48 * MB);      // 8 MB (later hb)
    unsigned short* hb    = vt;
    float*          pre   = (float*)(w8 + 56 * MB);               // 16 MB
    float*          h     = (float*)(w8 + 72 * MB);               // 16 MB

    const dim3 blk(256);

    convert_bf16<<<dim3(M_ * D_ / 8 / 256), blk, 0, stream>>>(x, xb);
    wtrans4<<<dim3(16, 16, 4), blk, 0, stream>>>(wq, wk, wv, wo, bq, bk, bv, wqkvt, wot, bqkv);
    wtrans<<<dim3(64, 16), blk, 0, stream>>>(w1, w1t, 512, 2048);
    wtrans<<<dim3(16, 64), blk, 0, stream>>>(w2, w2t, 2048, 512);

    // qkv = xb @ [wq|wk|wv] + b -> bf16 [M][1536]
    gemm_bf16<2,2,4,4,1,0,0,1><<<dim3(12, 64), blk, 0, stream>>>(
        xb, wqkvt, bqkv, nullptr, qkv, 512, 512, 512, 1536);

    vtrans<<<dim3(32, 32), blk, 0, stream>>>(qkv, vt);

    // causal flash attention (balanced pairs) -> ctx bf16
    attn_mfma<<<dim3(512), blk, 0, stream>>>(qkv, vt, ctx);

    // pre = x + ctx @ wo + bo (fp32, residual fused), 64x128 tiles
    gemm_bf16<1,4,4,2,0,0,1,1><<<dim3(4, 128), blk, 0, stream>>>(
        ctx, wot, bo, x, pre, 512, 512, 512, 512);

    // h = LN(pre), also bf16 copy hb
    ln_kernel<1,1><<<dim3(M_ / 4), blk, 0, stream>>>(pre, nullptr, g1, be1, h, hb);

    // ffn1 = relu(hb @ w1 + b1) -> bf16 [M][2048]
    gemm_bf16<2,2,4,4,1,1,0,1><<<dim3(16, 64), blk, 0, stream>>>(
        hb, w1t, b1, nullptr, ffn1b, 512, 512, 512, 2048);

    // ffn2 split-K=2: pre = h + ffn1[:,0:1024] @ w2[0:1024] + b2 ; pre2 = rest
    gemm_bf16<2,2,4,4,0,0,1,1><<<dim3(4, 64), blk, 0, stream>>>(
        ffn1b, w2t, b2, h, pre, 1024, 2048, 2048, 512);
    gemm_bf16<2,2,4,4,0,0,0,0><<<dim3(4, 64), blk, 0, stream>>>(
        ffn1b + 1024, w2t + 1024, nullptr, nullptr, pre2, 1024, 2048, 2048, 512);

    // out = LN(pre + pre2)
    ln_kernel<0,2><<<dim3(M_ / 4), blk, 0, stream>>>(pre, pre2, g2, be2, out, nullptr);
}